// Round 20
// baseline (352.710 us; speedup 1.0000x reference)
//
#include <hip/hip_runtime.h>
#include <hip/hip_bf16.h>
#include <stdint.h>

// ---------- types ----------
typedef unsigned short u16;
typedef __bf16 bf16x8 __attribute__((ext_vector_type(8)));
typedef u16   u16x8  __attribute__((ext_vector_type(8)));
typedef u16   u16x4  __attribute__((ext_vector_type(4)));
typedef u16   u16x2  __attribute__((ext_vector_type(2)));
typedef float f32x4  __attribute__((ext_vector_type(4)));

__device__ __forceinline__ u16 f2bf(float f) {
  union { float f; uint32_t u; } v; v.f = f;
  uint32_t r = v.u + 0x7fffu + ((v.u >> 16) & 1u);   // RNE
  return (u16)(r >> 16);
}
__device__ __forceinline__ float b2f(u16 u) {
  return __builtin_bit_cast(float, (uint32_t)u << 16);
}

// fast exact-grade GELU: x*sigmoid(1.5958x+0.0714x^3); max |err| ~3e-4 << tol
__device__ __forceinline__ float gelu_fast(float x) {
  float t = x * fmaf(x * x, 0.071354816f, 1.5957691216f);
  t = fminf(t, 80.0f);
  float e = exp2f(t * 1.44269504f);
  return x * e * __builtin_amdgcn_rcpf(e + 1.0f);
}

// async global->LDS, 16B per lane
typedef __attribute__((address_space(1))) void gvoid_t;
typedef __attribute__((address_space(3))) void lvoid_t;
__device__ __forceinline__ void gload_lds16(const void* g, void* l) {
  __builtin_amdgcn_global_load_lds((gvoid_t*)g, (lvoid_t*)l, 16, 0, 0);
}

// ---------- raw barriers / counted waits (T4) ----------
__device__ __forceinline__ void barrier_lgkm() {
  asm volatile("s_waitcnt lgkmcnt(0)\ns_barrier" ::: "memory");
}
__device__ __forceinline__ void bar_only() {
  asm volatile("s_barrier" ::: "memory");
}
template<int N> __device__ __forceinline__ void wait_vm() {
  asm volatile("s_waitcnt vmcnt(%0)" :: "n"(N) : "memory");
}

// ---------- LayerNorm (f32 in -> bf16 out), 1024 cols, one row per block ----------
__global__ __launch_bounds__(256)
void ln_kernel(const float* __restrict__ x, const float* __restrict__ g,
               const float* __restrict__ b, u16* __restrict__ out) {
  const int row = blockIdx.x;
  const int tid = threadIdx.x;
  const float* xr = x + (size_t)row * 1024;
  f32x4 v = *(const f32x4*)&xr[tid * 4];
  float s = v[0] + v[1] + v[2] + v[3];
  float q = v[0]*v[0] + v[1]*v[1] + v[2]*v[2] + v[3]*v[3];
  #pragma unroll
  for (int o = 32; o > 0; o >>= 1) { s += __shfl_xor(s, o); q += __shfl_xor(q, o); }
  __shared__ float ss[4], qq[4];
  if ((tid & 63) == 0) { ss[tid >> 6] = s; qq[tid >> 6] = q; }
  __syncthreads();
  s = ss[0] + ss[1] + ss[2] + ss[3];
  q = qq[0] + qq[1] + qq[2] + qq[3];
  float mu = s * (1.0f / 1024.0f);
  float var = q * (1.0f / 1024.0f) - mu * mu;
  float rstd = rsqrtf(var + 1e-5f);
  u16x4 o4;
  #pragma unroll
  for (int i = 0; i < 4; ++i)
    o4[i] = f2bf((v[i] - mu) * rstd * g[tid * 4 + i] + b[tid * 4 + i]);
  *(u16x4*)&out[(size_t)row * 1024 + tid * 4] = o4;
}

// ---------- ALL weight transposes in ONE launch ----------
__global__ __launch_bounds__(256)
void transpose_all(const float* __restrict__ wq, const float* __restrict__ wk,
                   const float* __restrict__ wv, const float* __restrict__ wo,
                   const float* __restrict__ w1, const float* __restrict__ w2,
                   u16* __restrict__ tqkv, u16* __restrict__ to,
                   u16* __restrict__ t1, u16* __restrict__ t2) {
  int id = blockIdx.x;                  // 0..12287
  const float* W; u16* T; int K, N, tn;
  if (id < 4096) {
    const int m = id >> 10; id &= 1023;
    K = 1024; N = 1024; tn = 32;
    switch (m) {
      case 0: W = wq; T = tqkv; break;
      case 1: W = wk; T = tqkv + 1024 * 1024; break;
      case 2: W = wv; T = tqkv + 2048 * 1024; break;
      default: W = wo; T = to; break;
    }
  } else if (id < 8192) {
    id -= 4096; W = w1; T = t1; K = 1024; N = 4096; tn = 128;
  } else {
    id -= 8192; W = w2; T = t2; K = 4096; N = 1024; tn = 32;
  }
  const int n0 = (id % tn) * 32, k0 = (id / tn) * 32;
  __shared__ float t[32][33];
  const int tx = threadIdx.x & 31, ty = threadIdx.x >> 5;
  #pragma unroll
  for (int i = 0; i < 4; ++i)
    t[ty + 8*i][tx] = W[(size_t)(k0 + ty + 8*i) * N + n0 + tx];
  __syncthreads();
  #pragma unroll
  for (int i = 0; i < 4; ++i)
    T[(size_t)(n0 + ty + 8*i) * K + k0 + tx] = f2bf(t[tx][ty + 8*i]);
}

// ---------- GEMM 128x128 (BK=32), 1D grid + XCD swizzle, LDS dbuf + counted vmcnt ----------
template<int EPI>
__global__ __launch_bounds__(256, 2)
void gemm_bt(const u16* __restrict__ A, const u16* __restrict__ Bt,
             void* __restrict__ out, const float* __restrict__ bias,
             const float* __restrict__ resid, int M, int N, int K, int gx) {
  __shared__ u16 As[2][128 * 32];
  __shared__ u16 Bs[2][128 * 32];
  const int tid = threadIdx.x;
  const int w = tid >> 6, l = tid & 63;
  const int qch = gridDim.x >> 3;
  const int sw = (blockIdx.x & 7) * qch + (blockIdx.x >> 3);
  const int bm = (sw % gx) * 128, bn = (sw / gx) * 128;
  const int wr = (w >> 1) * 64, wc = (w & 1) * 64;
  const int l15 = l & 15, lhi = l >> 4;
  f32x4 acc[4][4] = {};

  const int r4 = tid >> 2;
  const int c8 = (tid & 3) * 8;
  const u16* ga0 = A  + (size_t)(bm + r4) * K + c8;
  const u16* ga1 = ga0 + (size_t)64 * K;
  const u16* gb0 = Bt + (size_t)(bn + r4) * K + c8;
  const u16* gb1 = gb0 + (size_t)64 * K;

  const int arow = (wr + l15) * 32 + lhi * 8;
  const int brow = (wc + l15) * 32 + lhi * 8;

  auto stage = [&](int k0, int buf) {
    gload_lds16(ga0 + k0, &As[buf][(w * 16) * 32]);
    gload_lds16(ga1 + k0, &As[buf][(64 + w * 16) * 32]);
    gload_lds16(gb0 + k0, &Bs[buf][(w * 16) * 32]);
    gload_lds16(gb1 + k0, &Bs[buf][(64 + w * 16) * 32]);
  };

  const int nsteps = K >> 5;
  stage(0, 0);
  for (int s = 0; s < nsteps; ++s) {
    const int cur = s & 1;
    if (s + 1 < nsteps) { stage((s + 1) << 5, cur ^ 1); wait_vm<4>(); }
    else                { wait_vm<0>(); }
    bar_only();
    bf16x8 a[4], b[4];
    #pragma unroll
    for (int m = 0; m < 4; ++m) a[m] = *(const bf16x8*)&As[cur][arow + m * 16 * 32];
    #pragma unroll
    for (int n = 0; n < 4; ++n) b[n] = *(const bf16x8*)&Bs[cur][brow + n * 16 * 32];
    __builtin_amdgcn_s_setprio(1);
    #pragma unroll
    for (int m = 0; m < 4; ++m)
      #pragma unroll
      for (int n = 0; n < 4; ++n)
        acc[m][n] = __builtin_amdgcn_mfma_f32_16x16x32_bf16(a[m], b[n], acc[m][n], 0, 0, 0);
    __builtin_amdgcn_s_setprio(0);
    bar_only();
  }

  #pragma unroll
  for (int m = 0; m < 4; ++m) {
    #pragma unroll
    for (int n = 0; n < 4; ++n) {
      #pragma unroll
      for (int r = 0; r < 4; ++r) {
        const int grow = bm + wr + m * 16 + lhi * 4 + r;
        const int gcol = bn + wc + n * 16 + l15;
        float vv = acc[m][n][r];
        if constexpr (EPI >= 1) vv += bias[gcol];
        if constexpr (EPI == 1) vv = gelu_fast(vv);
        if constexpr (EPI == 2) {
          vv += resid[(size_t)grow * N + gcol];
          ((float*)out)[(size_t)grow * N + gcol] = vv;
        } else {
          ((u16*)out)[(size_t)grow * N + gcol] = f2bf(vv);
        }
      }
    }
  }
}

// ---------- GEMM 64x128, BK=64 (verified R14) ----------
template<int EPI>
__global__ __launch_bounds__(256, 2)
void gemm_bt64(const u16* __restrict__ A, const u16* __restrict__ Bt,
               void* __restrict__ out, const float* __restrict__ bias,
               const float* __restrict__ resid, int M, int N, int K, int gx) {
  __shared__ u16 As[2][64 * 64];        // 16 KB
  __shared__ u16 Bs[2][128 * 64];       // 32 KB
  const int tid = threadIdx.x;
  const int w = tid >> 6, l = tid & 63;
  const int qch = gridDim.x >> 3;
  const int sw = (blockIdx.x & 7) * qch + (blockIdx.x >> 3);
  const int bm = (sw % gx) * 64, bn = (sw / gx) * 128;
  const int wr = (w & 1) * 32, wc = (w >> 1) * 64;
  const int l15 = l & 15, lhi = l >> 4;
  f32x4 acc[2][4] = {};

  const int srow = tid >> 3;                     // 0..31
  const int schunk = (tid & 7) ^ (srow & 7);
  const u16* ga = A  + (size_t)(bm + srow) * K + schunk * 8;
  const u16* gb = Bt + (size_t)(bn + srow) * K + schunk * 8;

  auto stage = [&](int k0, int buf) {            // 6 gload_lds per thread
    gload_lds16(ga + k0,                  &As[buf][(w * 8) * 64]);
    gload_lds16(ga + k0 + (size_t)32 * K, &As[buf][(32 + w * 8) * 64]);
    gload_lds16(gb + k0,                  &Bs[buf][(w * 8) * 64]);
    gload_lds16(gb + k0 + (size_t)32 * K, &Bs[buf][(32 + w * 8) * 64]);
    gload_lds16(gb + k0 + (size_t)64 * K, &Bs[buf][(64 + w * 8) * 64]);
    gload_lds16(gb + k0 + (size_t)96 * K, &Bs[buf][(96 + w * 8) * 64]);
  };

  const int nsteps = K >> 6;
  stage(0, 0);
  for (int s = 0; s < nsteps; ++s) {
    const int cur = s & 1;
    if (s + 1 < nsteps) { stage((s + 1) << 6, cur ^ 1); wait_vm<6>(); }
    else                { wait_vm<0>(); }
    bar_only();
    bf16x8 a[2][2], b[4][2];
    #pragma unroll
    for (int m = 0; m < 2; ++m) {
      const int row = wr + m * 16 + l15;
      #pragma unroll
      for (int ks = 0; ks < 2; ++ks)
        a[m][ks] = *(const bf16x8*)&As[cur][row * 64 + (((ks * 4 + lhi) ^ (row & 7)) * 8)];
    }
    #pragma unroll
    for (int n = 0; n < 4; ++n) {
      const int row = wc + n * 16 + l15;
      #pragma unroll
      for (int ks = 0; ks < 2; ++ks)
        b[n][ks] = *(const bf16x8*)&Bs[cur][row * 64 + (((ks * 4 + lhi) ^ (row & 7)) * 8)];
    }
    __builtin_amdgcn_s_setprio(1);
    #pragma unroll
    for (int ks = 0; ks < 2; ++ks)
      #pragma unroll
      for (int m = 0; m < 2; ++m)
        #pragma unroll
        for (int n = 0; n < 4; ++n)
          acc[m][n] = __builtin_amdgcn_mfma_f32_16x16x32_bf16(a[m][ks], b[n][ks], acc[m][n], 0, 0, 0);
    __builtin_amdgcn_s_setprio(0);
    bar_only();
  }

  #pragma unroll
  for (int m = 0; m < 2; ++m) {
    #pragma unroll
    for (int n = 0; n < 4; ++n) {
      #pragma unroll
      for (int r = 0; r < 4; ++r) {
        const int grow = bm + wr + m * 16 + lhi * 4 + r;
        const int gcol = bn + wc + n * 16 + l15;
        float vv = acc[m][n][r];
        if constexpr (EPI >= 1) vv += bias[gcol];
        if constexpr (EPI == 1) vv = gelu_fast(vv);
        if constexpr (EPI == 2) {
          vv += resid[(size_t)grow * N + gcol];
          ((float*)out)[(size_t)grow * N + gcol] = vv;
        } else {
          ((u16*)out)[(size_t)grow * N + gcol] = f2bf(vv);
        }
      }
    }
  }
}

// ---------- fused flash attention v16: QBLK=128, 8 waves, KV-SPLIT-2 ----------
// Fix vs R18: softmax sums are per (row, HEAD) -> ssc layout [half][4096][16].
// Fixed-shift softmax (exp2(p*L2E-30), validated R13) makes partials additive.
// 1024 blocks -> 3 blocks/CU x 8 waves = 24 waves/CU (1.5x TLP vs R17).
#define SWZ(row) ((((row) & 7) ^ (((row) >> 3) & 7)) << 3)

__global__ __launch_bounds__(512)
void attn_kernel(const u16* __restrict__ qkv, const float* __restrict__ bias,
                 u16* __restrict__ osc, float* __restrict__ ssc) {
  const int qt = blockIdx.x;            // 0..15 (128 q-rows)
  const int bh = blockIdx.y;            // 0..31
  const int half = blockIdx.z;          // 0..1 (KV half)
  const int b = bh >> 4, h = bh & 15;
  const int tid = threadIdx.x, w = tid >> 6, l = tid & 63;   // w: 0..7
  const int l15 = l & 15, lhi = l >> 4;
  const size_t ld = 3072;
  const float L2E = 1.44269504f;
  const int kv_base = half * 1024;

  __shared__ u16 Kl[2][4096];           // dbuf [key][64] swizzled
  __shared__ u16 Vt[2][4096];           // dbuf [d][64] (V^T) swizzled
  __shared__ u16 Pl[8][1024];           // per wave [qrow16][64keys] swizzled

  const u16* qp = qkv;
  const u16* kp = qkv + 1024;
  const u16* vp = qkv + 2048;

  const bool stager = tid < 256;        // waves 0-3 (wave-uniform)
  const int key2 = (tid >> 3) * 2, dg8 = (tid & 7) * 8;   // valid for tid<256
  const u16* kbase = kp + ((size_t)b * 2048 + kv_base + key2) * ld + h * 64 + dg8;
  const u16* vbase = vp + ((size_t)b * 2048 + kv_base + key2) * ld + h * 64 + dg8;

  bf16x8 qf0, qf1;
  {
    const u16* qrow = qp + ((size_t)b * 2048 + qt * 128 + w * 16 + l15) * ld + h * 64 + lhi * 8;
    qf0 = *(const bf16x8*)qrow;
    qf1 = *(const bf16x8*)(qrow + 32);
  }

  const float* bp = bias + ((size_t)h * 2048 + qt * 128 + w * 16 + l15) * 2048 + kv_base + lhi * 4;

  float s_run = 0.f;                    // per-lane PARTIAL (16 of 64 keys/iter)
  f32x4 octx[4] = {};

  u16x8 kpf[2], vpf[2];
  f32x4 bfA[4], bfB[4];

  auto load_kv = [&](int kv) {          // kv relative to kv_base
    kpf[0] = *(const u16x8*)(kbase + (size_t)kv * ld);
    kpf[1] = *(const u16x8*)(kbase + (size_t)(kv + 1) * ld);
    vpf[0] = *(const u16x8*)(vbase + (size_t)kv * ld);
    vpf[1] = *(const u16x8*)(vbase + (size_t)(kv + 1) * ld);
  };
  auto load_bias = [&](f32x4 (&bv)[4]) {
    #pragma unroll
    for (int nf = 0; nf < 4; ++nf) bv[nf] = *(const f32x4*)(bp + nf * 16);
    bp += 64;
  };
  auto store_kv = [&](u16* Kd, u16* Vd) {
    *(u16x8*)&Kd[(key2)     * 64 + (dg8 ^ SWZ(key2))]     = kpf[0];
    *(u16x8*)&Kd[(key2 + 1) * 64 + (dg8 ^ SWZ(key2 + 1))] = kpf[1];
    #pragma unroll
    for (int i = 0; i < 8; ++i) {
      const int d = dg8 + i;
      u16x2 vq = { vpf[0][i], vpf[1][i] };
      *(u16x2*)&Vd[d * 64 + (key2 ^ SWZ(d))] = vq;
    }
  };

  if (stager) {
    load_kv(0);
    store_kv(Kl[0], Vt[0]);
    load_kv(64);
  }
  load_bias(bfA);
  load_bias(bfB);
  barrier_lgkm();

  auto iter = [&](int it, int cur, f32x4 (&bc)[4]) {
    if (stager) {
      if (it < 15) store_kv(Kl[cur ^ 1], Vt[cur ^ 1]);
      if (it < 14) load_kv((it + 2) * 64);
    }

    // QK^T, swapped operands: sa[nf][j] = S[key=nf*16+lhi*4+j][qrow=l15]
    f32x4 sa[4] = {};
    __builtin_amdgcn_s_setprio(1);
    #pragma unroll
    for (int nf = 0; nf < 4; ++nf) {
      const int row = nf * 16 + l15;
      const int s = SWZ(row);
      bf16x8 kf0 = *(const bf16x8*)&Kl[cur][row * 64 + ((lhi * 8) ^ s)];
      bf16x8 kf1 = *(const bf16x8*)&Kl[cur][row * 64 + ((32 + lhi * 8) ^ s)];
      sa[nf] = __builtin_amdgcn_mfma_f32_16x16x32_bf16(kf0, qf0, sa[nf], 0, 0, 0);
      sa[nf] = __builtin_amdgcn_mfma_f32_16x16x32_bf16(kf1, qf1, sa[nf], 0, 0, 0);
    }
    __builtin_amdgcn_s_setprio(0);

    f32x4 p[4];
    #pragma unroll
    for (int nf = 0; nf < 4; ++nf)
      #pragma unroll
      for (int j = 0; j < 4; ++j)
        p[nf][j] = fmaf(sa[nf][j], 0.125f, bc[nf][j]);
    if (it < 14) load_bias(bc);

    // exp with FIXED shift (no max tracking; validated R13) + partial sum
    f32x4 e[4];
    #pragma unroll
    for (int nf = 0; nf < 4; ++nf)
      #pragma unroll
      for (int j = 0; j < 4; ++j)
        e[nf][j] = exp2f(fmaf(p[nf][j], L2E, -30.0f));
    f32x4 s4;
    #pragma unroll
    for (int j = 0; j < 4; ++j)
      s4[j] = (e[0][j] + e[1][j]) + (e[2][j] + e[3][j]);
    s_run += (s4[0] + s4[1]) + (s4[2] + s4[3]);

    // P -> per-wave LDS
    {
      const int sw = SWZ(l15);
      const int base = l15 * 64;
      #pragma unroll
      for (int nf = 0; nf < 4; ++nf) {
        u16x4 pk = { __builtin_bit_cast(u16, (__bf16)e[nf][0]),
                     __builtin_bit_cast(u16, (__bf16)e[nf][1]),
                     __builtin_bit_cast(u16, (__bf16)e[nf][2]),
                     __builtin_bit_cast(u16, (__bf16)e[nf][3]) };
        *(u16x4*)&Pl[w][base + ((nf * 16 + lhi * 4) ^ sw)] = pk;
      }
    }

    // PV from cur
    __builtin_amdgcn_s_setprio(1);
    #pragma unroll
    for (int ks = 0; ks < 2; ++ks) {
      bf16x8 pa = *(const bf16x8*)&Pl[w][l15 * 64 + ((ks * 32 + lhi * 8) ^ SWZ(l15))];
      #pragma unroll
      for (int nf = 0; nf < 4; ++nf) {
        const int row = nf * 16 + l15;
        bf16x8 bv = *(const bf16x8*)&Vt[cur][row * 64 + ((ks * 32 + lhi * 8) ^ SWZ(row))];
        octx[nf] = __builtin_amdgcn_mfma_f32_16x16x32_bf16(pa, bv, octx[nf], 0, 0, 0);
      }
    }
    __builtin_amdgcn_s_setprio(0);

    barrier_lgkm();
  };

  for (int i2 = 0; i2 < 8; ++i2) {
    iter(2 * i2,     0, bfA);
    iter(2 * i2 + 1, 1, bfB);
  }

  // ---- write partials: per-(row,head) sums (f32) + raw octx (bf16) ----
  s_run += __shfl_xor(s_run, 16);
  s_run += __shfl_xor(s_run, 32);       // row total for qrow=l15 (this half)
  const int rowbase = b * 2048 + qt * 128 + w * 16;
  if (lhi == 0)
    ssc[((size_t)half * 4096 + rowbase + l15) * 16 + h] = s_run;
  const size_t obase = (size_t)half * 4096 * 1024;
  #pragma unroll
  for (int nf = 0; nf < 4; ++nf)
    #pragma unroll
    for (int r = 0; r < 4; ++r) {
      const int grow = rowbase + lhi * 4 + r;
      const int gcol = h * 64 + nf * 16 + l15;
      osc[obase + (size_t)grow * 1024 + gcol] = f2bf(octx[nf][r]);
    }
}

// ---------- combine the two KV halves: ctx = (o0+o1)/(s0+s1), per (row,head) ----------
__global__ __launch_bounds__(256)
void attn_combine(const u16* __restrict__ osc, const float* __restrict__ ssc,
                  u16* __restrict__ ctx) {
  const int row = blockIdx.x;           // 0..4095
  const int tid = threadIdx.x;
  const int head = tid >> 4;            // 4 cols per thread, 64-col heads
  const float inv = 1.0f / (ssc[(size_t)row * 16 + head] +
                            ssc[((size_t)4096 + row) * 16 + head]);
  const size_t off = (size_t)row * 1024 + tid * 4;
  u16x4 a0 = *(const u16x4*)&osc[off];
  u16x4 a1 = *(const u16x4*)&osc[(size_t)4096 * 1024 + off];
  u16x4 o;
  #pragma unroll
  for (int i = 0; i < 4; ++i)
    o[i] = f2bf((b2f(a0[i]) + b2f(a1[i])) * inv);
  *(u16x4*)&ctx[off] = o;
}

// ---------- launch ----------
extern "C" void kernel_launch(void* const* d_in, const int* in_sizes, int n_in,
                              void* d_out, int out_size, void* d_ws, size_t ws_size,
                              hipStream_t stream) {
  const float* x    = (const float*)d_in[0];
  const float* rb   = (const float*)d_in[1];
  const float* wq   = (const float*)d_in[2];
  const float* wk   = (const float*)d_in[3];
  const float* wv   = (const float*)d_in[4];
  const float* wo   = (const float*)d_in[5];
  const float* wo_b = (const float*)d_in[6];
  const float* w1   = (const float*)d_in[7];
  const float* b1   = (const float*)d_in[8];
  const float* w2   = (const float*)d_in[9];
  const float* b2   = (const float*)d_in[10];
  const float* ln1g = (const float*)d_in[11];
  const float* ln1b = (const float*)d_in[12];
  const float* ln2g = (const float*)d_in[13];
  const float* ln2b = (const float*)d_in[14];

  char* ws = (char*)d_ws;
  u16*   xn    = (u16*)(ws + 0);                    //  8 MB
  u16*   qkvb  = (u16*)(ws + (8u << 20));           // 24 MB (8..32)
  u16*   hbuf  = (u16*)(ws + (8u << 20));           // 32 MB (reuses qkv+ctx, FFN phase)
  u16*   ctxb  = (u16*)(ws + (32u << 20));          //  8 MB (32..40)
  u16*   osc   = (u16*)(ws + (40u << 20));          // 16 MB (40..56) attn partials (x1 region, free during attn)
  float* ssc   = (float*)(ws + (56u << 20));        // 512 KB (56..56.5) per-(row,head) sums
  float* x1    = (float*)(ws + (40u << 20));        // 16 MB (40..56) written AFTER combine
  u16*   wqkvt = (u16*)(ws + (57u << 20));          //  6 MB (57..63)
  u16*   wot   = (u16*)(ws + (63u << 20));          //  2 MB (63..65)
  u16*   w1t   = (u16*)(ws + (65u << 20));          //  8 MB (65..73)
  u16*   w2t   = (u16*)(ws + (73u << 20));          //  8 MB (73..81)

  transpose_all<<<12288, 256, 0, stream>>>(wq, wk, wv, wo, w1, w2,
                                           wqkvt, wot, w1t, w2t);

  ln_kernel<<<4096, 256, 0, stream>>>(x, ln1g, ln1b, xn);
  gemm_bt<0><<<768, 256, 0, stream>>>(xn, wqkvt, qkvb, nullptr, nullptr, 4096, 3072, 1024, 32);
  attn_kernel<<<dim3(16, 32, 2), 512, 0, stream>>>(qkvb, rb, osc, ssc);
  attn_combine<<<4096, 256, 0, stream>>>(osc, ssc, ctxb);
  gemm_bt64<2><<<512, 256, 0, stream>>>(ctxb, wot, x1, wo_b, x, 4096, 1024, 1024, 64);
  ln_kernel<<<4096, 256, 0, stream>>>(x1, ln2g, ln2b, xn);
  gemm_bt<1><<<1024, 256, 0, stream>>>(xn, w1t, hbuf, b1, nullptr, 4096, 4096, 1024, 32);
  gemm_bt64<2><<<512, 256, 0, stream>>>(hbuf, w2t, (float*)d_out, b2, x1, 4096, 1024, 4096, 64);

  (void)in_sizes; (void)n_in; (void)out_size; (void)ws_size;
}

// Round 21
// 351.392 us; speedup vs baseline: 1.0038x; 1.0038x over previous
//
#include <hip/hip_runtime.h>
#include <hip/hip_bf16.h>
#include <stdint.h>

// ---------- types ----------
typedef unsigned short u16;
typedef __bf16 bf16x8 __attribute__((ext_vector_type(8)));
typedef u16   u16x8  __attribute__((ext_vector_type(8)));
typedef u16   u16x4  __attribute__((ext_vector_type(4)));
typedef u16   u16x2  __attribute__((ext_vector_type(2)));
typedef float f32x4  __attribute__((ext_vector_type(4)));

__device__ __forceinline__ u16 f2bf(float f) {
  union { float f; uint32_t u; } v; v.f = f;
  uint32_t r = v.u + 0x7fffu + ((v.u >> 16) & 1u);   // RNE
  return (u16)(r >> 16);
}

// fast exact-grade GELU: x*sigmoid(1.5958x+0.0714x^3); max |err| ~3e-4 << tol
__device__ __forceinline__ float gelu_fast(float x) {
  float t = x * fmaf(x * x, 0.071354816f, 1.5957691216f);
  t = fminf(t, 80.0f);
  float e = exp2f(t * 1.44269504f);
  return x * e * __builtin_amdgcn_rcpf(e + 1.0f);
}

// async global->LDS, 16B per lane
typedef __attribute__((address_space(1))) void gvoid_t;
typedef __attribute__((address_space(3))) void lvoid_t;
__device__ __forceinline__ void gload_lds16(const void* g, void* l) {
  __builtin_amdgcn_global_load_lds((gvoid_t*)g, (lvoid_t*)l, 16, 0, 0);
}

// ---------- raw barriers / counted waits (T4) ----------
__device__ __forceinline__ void barrier_lgkm() {
  asm volatile("s_waitcnt lgkmcnt(0)\ns_barrier" ::: "memory");
}
__device__ __forceinline__ void bar_only() {
  asm volatile("s_barrier" ::: "memory");
}
template<int N> __device__ __forceinline__ void wait_vm() {
  asm volatile("s_waitcnt vmcnt(%0)" :: "n"(N) : "memory");
}

// ---------- LayerNorm (f32 in -> bf16 out), 1024 cols, one row per block ----------
__global__ __launch_bounds__(256)
void ln_kernel(const float* __restrict__ x, const float* __restrict__ g,
               const float* __restrict__ b, u16* __restrict__ out) {
  const int row = blockIdx.x;
  const int tid = threadIdx.x;
  const float* xr = x + (size_t)row * 1024;
  f32x4 v = *(const f32x4*)&xr[tid * 4];
  float s = v[0] + v[1] + v[2] + v[3];
  float q = v[0]*v[0] + v[1]*v[1] + v[2]*v[2] + v[3]*v[3];
  #pragma unroll
  for (int o = 32; o > 0; o >>= 1) { s += __shfl_xor(s, o); q += __shfl_xor(q, o); }
  __shared__ float ss[4], qq[4];
  if ((tid & 63) == 0) { ss[tid >> 6] = s; qq[tid >> 6] = q; }
  __syncthreads();
  s = ss[0] + ss[1] + ss[2] + ss[3];
  q = qq[0] + qq[1] + qq[2] + qq[3];
  float mu = s * (1.0f / 1024.0f);
  float var = q * (1.0f / 1024.0f) - mu * mu;
  float rstd = rsqrtf(var + 1e-5f);
  u16x4 o4;
  #pragma unroll
  for (int i = 0; i < 4; ++i)
    o4[i] = f2bf((v[i] - mu) * rstd * g[tid * 4 + i] + b[tid * 4 + i]);
  *(u16x4*)&out[(size_t)row * 1024 + tid * 4] = o4;
}

// ---------- ALL weight transposes in ONE launch ----------
__global__ __launch_bounds__(256)
void transpose_all(const float* __restrict__ wq, const float* __restrict__ wk,
                   const float* __restrict__ wv, const float* __restrict__ wo,
                   const float* __restrict__ w1, const float* __restrict__ w2,
                   u16* __restrict__ tqkv, u16* __restrict__ to,
                   u16* __restrict__ t1, u16* __restrict__ t2) {
  int id = blockIdx.x;                  // 0..12287
  const float* W; u16* T; int K, N, tn;
  if (id < 4096) {
    const int m = id >> 10; id &= 1023;
    K = 1024; N = 1024; tn = 32;
    switch (m) {
      case 0: W = wq; T = tqkv; break;
      case 1: W = wk; T = tqkv + 1024 * 1024; break;
      case 2: W = wv; T = tqkv + 2048 * 1024; break;
      default: W = wo; T = to; break;
    }
  } else if (id < 8192) {
    id -= 4096; W = w1; T = t1; K = 1024; N = 4096; tn = 128;
  } else {
    id -= 8192; W = w2; T = t2; K = 4096; N = 1024; tn = 32;
  }
  const int n0 = (id % tn) * 32, k0 = (id / tn) * 32;
  __shared__ float t[32][33];
  const int tx = threadIdx.x & 31, ty = threadIdx.x >> 5;
  #pragma unroll
  for (int i = 0; i < 4; ++i)
    t[ty + 8*i][tx] = W[(size_t)(k0 + ty + 8*i) * N + n0 + tx];
  __syncthreads();
  #pragma unroll
  for (int i = 0; i < 4; ++i)
    T[(size_t)(n0 + ty + 8*i) * K + k0 + tx] = f2bf(t[tx][ty + 8*i]);
}

// ---------- GEMM 128x128 (BK=32), 1D grid + XCD swizzle, LDS dbuf + counted vmcnt ----------
template<int EPI>
__global__ __launch_bounds__(256, 2)
void gemm_bt(const u16* __restrict__ A, const u16* __restrict__ Bt,
             void* __restrict__ out, const float* __restrict__ bias,
             const float* __restrict__ resid, int M, int N, int K, int gx) {
  __shared__ u16 As[2][128 * 32];
  __shared__ u16 Bs[2][128 * 32];
  const int tid = threadIdx.x;
  const int w = tid >> 6, l = tid & 63;
  const int qch = gridDim.x >> 3;
  const int sw = (blockIdx.x & 7) * qch + (blockIdx.x >> 3);
  const int bm = (sw % gx) * 128, bn = (sw / gx) * 128;
  const int wr = (w >> 1) * 64, wc = (w & 1) * 64;
  const int l15 = l & 15, lhi = l >> 4;
  f32x4 acc[4][4] = {};

  const int r4 = tid >> 2;
  const int c8 = (tid & 3) * 8;
  const u16* ga0 = A  + (size_t)(bm + r4) * K + c8;
  const u16* ga1 = ga0 + (size_t)64 * K;
  const u16* gb0 = Bt + (size_t)(bn + r4) * K + c8;
  const u16* gb1 = gb0 + (size_t)64 * K;

  const int arow = (wr + l15) * 32 + lhi * 8;
  const int brow = (wc + l15) * 32 + lhi * 8;

  auto stage = [&](int k0, int buf) {
    gload_lds16(ga0 + k0, &As[buf][(w * 16) * 32]);
    gload_lds16(ga1 + k0, &As[buf][(64 + w * 16) * 32]);
    gload_lds16(gb0 + k0, &Bs[buf][(w * 16) * 32]);
    gload_lds16(gb1 + k0, &Bs[buf][(64 + w * 16) * 32]);
  };

  const int nsteps = K >> 5;
  stage(0, 0);
  for (int s = 0; s < nsteps; ++s) {
    const int cur = s & 1;
    if (s + 1 < nsteps) { stage((s + 1) << 5, cur ^ 1); wait_vm<4>(); }
    else                { wait_vm<0>(); }
    bar_only();
    bf16x8 a[4], b[4];
    #pragma unroll
    for (int m = 0; m < 4; ++m) a[m] = *(const bf16x8*)&As[cur][arow + m * 16 * 32];
    #pragma unroll
    for (int n = 0; n < 4; ++n) b[n] = *(const bf16x8*)&Bs[cur][brow + n * 16 * 32];
    __builtin_amdgcn_s_setprio(1);
    #pragma unroll
    for (int m = 0; m < 4; ++m)
      #pragma unroll
      for (int n = 0; n < 4; ++n)
        acc[m][n] = __builtin_amdgcn_mfma_f32_16x16x32_bf16(a[m], b[n], acc[m][n], 0, 0, 0);
    __builtin_amdgcn_s_setprio(0);
    bar_only();
  }

  #pragma unroll
  for (int m = 0; m < 4; ++m) {
    #pragma unroll
    for (int n = 0; n < 4; ++n) {
      #pragma unroll
      for (int r = 0; r < 4; ++r) {
        const int grow = bm + wr + m * 16 + lhi * 4 + r;
        const int gcol = bn + wc + n * 16 + l15;
        float vv = acc[m][n][r];
        if constexpr (EPI >= 1) vv += bias[gcol];
        if constexpr (EPI == 1) vv = gelu_fast(vv);
        if constexpr (EPI == 2) {
          vv += resid[(size_t)grow * N + gcol];
          ((float*)out)[(size_t)grow * N + gcol] = vv;
        } else {
          ((u16*)out)[(size_t)grow * N + gcol] = f2bf(vv);
        }
      }
    }
  }
}

// ---------- GEMM 64x128, BK=64 (verified R14) ----------
template<int EPI>
__global__ __launch_bounds__(256, 2)
void gemm_bt64(const u16* __restrict__ A, const u16* __restrict__ Bt,
               void* __restrict__ out, const float* __restrict__ bias,
               const float* __restrict__ resid, int M, int N, int K, int gx) {
  __shared__ u16 As[2][64 * 64];        // 16 KB
  __shared__ u16 Bs[2][128 * 64];       // 32 KB
  const int tid = threadIdx.x;
  const int w = tid >> 6, l = tid & 63;
  const int qch = gridDim.x >> 3;
  const int sw = (blockIdx.x & 7) * qch + (blockIdx.x >> 3);
  const int bm = (sw % gx) * 64, bn = (sw / gx) * 128;
  const int wr = (w & 1) * 32, wc = (w >> 1) * 64;
  const int l15 = l & 15, lhi = l >> 4;
  f32x4 acc[2][4] = {};

  const int srow = tid >> 3;                     // 0..31
  const int schunk = (tid & 7) ^ (srow & 7);
  const u16* ga = A  + (size_t)(bm + srow) * K + schunk * 8;
  const u16* gb = Bt + (size_t)(bn + srow) * K + schunk * 8;

  auto stage = [&](int k0, int buf) {            // 6 gload_lds per thread
    gload_lds16(ga + k0,                  &As[buf][(w * 8) * 64]);
    gload_lds16(ga + k0 + (size_t)32 * K, &As[buf][(32 + w * 8) * 64]);
    gload_lds16(gb + k0,                  &Bs[buf][(w * 8) * 64]);
    gload_lds16(gb + k0 + (size_t)32 * K, &Bs[buf][(32 + w * 8) * 64]);
    gload_lds16(gb + k0 + (size_t)64 * K, &Bs[buf][(64 + w * 8) * 64]);
    gload_lds16(gb + k0 + (size_t)96 * K, &Bs[buf][(96 + w * 8) * 64]);
  };

  const int nsteps = K >> 6;
  stage(0, 0);
  for (int s = 0; s < nsteps; ++s) {
    const int cur = s & 1;
    if (s + 1 < nsteps) { stage((s + 1) << 6, cur ^ 1); wait_vm<6>(); }
    else                { wait_vm<0>(); }
    bar_only();
    bf16x8 a[2][2], b[4][2];
    #pragma unroll
    for (int m = 0; m < 2; ++m) {
      const int row = wr + m * 16 + l15;
      #pragma unroll
      for (int ks = 0; ks < 2; ++ks)
        a[m][ks] = *(const bf16x8*)&As[cur][row * 64 + (((ks * 4 + lhi) ^ (row & 7)) * 8)];
    }
    #pragma unroll
    for (int n = 0; n < 4; ++n) {
      const int row = wc + n * 16 + l15;
      #pragma unroll
      for (int ks = 0; ks < 2; ++ks)
        b[n][ks] = *(const bf16x8*)&Bs[cur][row * 64 + (((ks * 4 + lhi) ^ (row & 7)) * 8)];
    }
    __builtin_amdgcn_s_setprio(1);
    #pragma unroll
    for (int ks = 0; ks < 2; ++ks)
      #pragma unroll
      for (int m = 0; m < 2; ++m)
        #pragma unroll
        for (int n = 0; n < 4; ++n)
          acc[m][n] = __builtin_amdgcn_mfma_f32_16x16x32_bf16(a[m][ks], b[n][ks], acc[m][n], 0, 0, 0);
    __builtin_amdgcn_s_setprio(0);
    bar_only();
  }

  #pragma unroll
  for (int m = 0; m < 2; ++m) {
    #pragma unroll
    for (int n = 0; n < 4; ++n) {
      #pragma unroll
      for (int r = 0; r < 4; ++r) {
        const int grow = bm + wr + m * 16 + lhi * 4 + r;
        const int gcol = bn + wc + n * 16 + l15;
        float vv = acc[m][n][r];
        if constexpr (EPI >= 1) vv += bias[gcol];
        if constexpr (EPI == 1) vv = gelu_fast(vv);
        if constexpr (EPI == 2) {
          vv += resid[(size_t)grow * N + gcol];
          ((float*)out)[(size_t)grow * N + gcol] = vv;
        } else {
          ((u16*)out)[(size_t)grow * N + gcol] = f2bf(vv);
        }
      }
    }
  }
}

// ---------- fused flash attention v14: QBLK=128, 8 waves (best-measured config) ----------
#define SWZ(row) ((((row) & 7) ^ (((row) >> 3) & 7)) << 3)

__global__ __launch_bounds__(512)
void attn_kernel(const u16* __restrict__ qkv, const float* __restrict__ bias,
                 u16* __restrict__ ctx) {
  const int qt = blockIdx.x;            // 0..15 (128 q-rows)
  const int bh = blockIdx.y;            // 0..31
  const int b = bh >> 4, h = bh & 15;
  const int tid = threadIdx.x, w = tid >> 6, l = tid & 63;   // w: 0..7
  const int l15 = l & 15, lhi = l >> 4;
  const size_t ld = 3072;
  const float L2E = 1.44269504f;
  const float THR = 5.545177f;          // 8 in log2 units

  __shared__ u16 Kl[2][4096];           // dbuf [key][64] swizzled
  __shared__ u16 Vt[2][4096];           // dbuf [d][64] (V^T) swizzled
  __shared__ u16 Pl[8][1024];           // per wave [qrow16][64keys] swizzled

  const u16* qp = qkv;
  const u16* kp = qkv + 1024;
  const u16* vp = qkv + 2048;

  const bool stager = tid < 256;        // waves 0-3 (wave-uniform)
  const int key2 = (tid >> 3) * 2, dg8 = (tid & 7) * 8;   // valid for tid<256
  const u16* kbase = kp + ((size_t)b * 2048 + key2) * ld + h * 64 + dg8;
  const u16* vbase = vp + ((size_t)b * 2048 + key2) * ld + h * 64 + dg8;

  bf16x8 qf0, qf1;
  {
    const u16* qrow = qp + ((size_t)b * 2048 + qt * 128 + w * 16 + l15) * ld + h * 64 + lhi * 8;
    qf0 = *(const bf16x8*)qrow;
    qf1 = *(const bf16x8*)(qrow + 32);
  }

  const float* bp = bias + ((size_t)h * 2048 + qt * 128 + w * 16 + l15) * 2048 + lhi * 4;

  float m_run = -1e30f, s_run = 0.f;    // s_run: per-lane PARTIAL (16 of 64 keys)
  f32x4 octx[4] = {};

  u16x8 kpf[2], vpf[2];
  f32x4 bfA[4], bfB[4];

  auto load_kv = [&](int kv) {          // staging waves only
    kpf[0] = *(const u16x8*)(kbase + (size_t)kv * ld);
    kpf[1] = *(const u16x8*)(kbase + (size_t)(kv + 1) * ld);
    vpf[0] = *(const u16x8*)(vbase + (size_t)kv * ld);
    vpf[1] = *(const u16x8*)(vbase + (size_t)(kv + 1) * ld);
  };
  auto load_bias = [&](f32x4 (&bv)[4]) {
    #pragma unroll
    for (int nf = 0; nf < 4; ++nf) bv[nf] = *(const f32x4*)(bp + nf * 16);
    bp += 64;
  };
  auto store_kv = [&](u16* Kd, u16* Vd) {
    *(u16x8*)&Kd[(key2)     * 64 + (dg8 ^ SWZ(key2))]     = kpf[0];
    *(u16x8*)&Kd[(key2 + 1) * 64 + (dg8 ^ SWZ(key2 + 1))] = kpf[1];
    #pragma unroll
    for (int i = 0; i < 8; ++i) {
      const int d = dg8 + i;
      u16x2 vq = { vpf[0][i], vpf[1][i] };
      *(u16x2*)&Vd[d * 64 + (key2 ^ SWZ(d))] = vq;
    }
  };

  if (stager) {
    load_kv(0);
    store_kv(Kl[0], Vt[0]);
    load_kv(64);
  }
  load_bias(bfA);
  load_bias(bfB);
  barrier_lgkm();

  auto iter = [&](int it, int cur, f32x4 (&bc)[4]) {
    if (stager) {
      if (it < 31) store_kv(Kl[cur ^ 1], Vt[cur ^ 1]);
      if (it < 30) load_kv((it + 2) * 64);
    }

    // QK^T, swapped operands: sa[nf][j] = S[key=nf*16+lhi*4+j][qrow=l15]
    f32x4 sa[4] = {};
    __builtin_amdgcn_s_setprio(1);
    #pragma unroll
    for (int nf = 0; nf < 4; ++nf) {
      const int row = nf * 16 + l15;
      const int s = SWZ(row);
      bf16x8 kf0 = *(const bf16x8*)&Kl[cur][row * 64 + ((lhi * 8) ^ s)];
      bf16x8 kf1 = *(const bf16x8*)&Kl[cur][row * 64 + ((32 + lhi * 8) ^ s)];
      sa[nf] = __builtin_amdgcn_mfma_f32_16x16x32_bf16(kf0, qf0, sa[nf], 0, 0, 0);
      sa[nf] = __builtin_amdgcn_mfma_f32_16x16x32_bf16(kf1, qf1, sa[nf], 0, 0, 0);
    }
    __builtin_amdgcn_s_setprio(0);

    f32x4 p[4];
    #pragma unroll
    for (int nf = 0; nf < 4; ++nf)
      #pragma unroll
      for (int j = 0; j < 4; ++j)
        p[nf][j] = fmaf(sa[nf][j], 0.125f, bc[nf][j]);
    if (it < 30) load_bias(bc);

    // lane-local max guard; cross-lane reduce only when triggered
    f32x4 m4;
    #pragma unroll
    for (int j = 0; j < 4; ++j)
      m4[j] = fmaxf(fmaxf(p[0][j], p[1][j]), fmaxf(p[2][j], p[3][j]));
    const float mloc = fmaxf(fmaxf(m4[0], m4[1]), fmaxf(m4[2], m4[3]));
    if (__any(mloc > m_run + THR)) {
      float mx = fmaxf(mloc, __shfl_xor(mloc, 16));
      mx = fmaxf(mx, __shfl_xor(mx, 32));
      if (mx > m_run + THR) {
        const float fs = exp2f((m_run - mx) * L2E);
        s_run *= fs;
        const float f0 = __shfl(fs, lhi * 4 + 0);
        const float f1 = __shfl(fs, lhi * 4 + 1);
        const float f2 = __shfl(fs, lhi * 4 + 2);
        const float f3 = __shfl(fs, lhi * 4 + 3);
        #pragma unroll
        for (int nf = 0; nf < 4; ++nf) {
          octx[nf][0] *= f0; octx[nf][1] *= f1;
          octx[nf][2] *= f2; octx[nf][3] *= f3;
        }
        m_run = mx;
      }
    }

    // exp + per-lane partial sum (no cross-lane ops)
    const float nml = -m_run * L2E;
    f32x4 e[4];
    #pragma unroll
    for (int nf = 0; nf < 4; ++nf)
      #pragma unroll
      for (int j = 0; j < 4; ++j)
        e[nf][j] = exp2f(fmaf(p[nf][j], L2E, nml));
    f32x4 s4;
    #pragma unroll
    for (int j = 0; j < 4; ++j)
      s4[j] = (e[0][j] + e[1][j]) + (e[2][j] + e[3][j]);
    s_run += (s4[0] + s4[1]) + (s4[2] + s4[3]);

    // P -> per-wave LDS
    {
      const int sw = SWZ(l15);
      const int base = l15 * 64;
      #pragma unroll
      for (int nf = 0; nf < 4; ++nf) {
        u16x4 pk = { __builtin_bit_cast(u16, (__bf16)e[nf][0]),
                     __builtin_bit_cast(u16, (__bf16)e[nf][1]),
                     __builtin_bit_cast(u16, (__bf16)e[nf][2]),
                     __builtin_bit_cast(u16, (__bf16)e[nf][3]) };
        *(u16x4*)&Pl[w][base + ((nf * 16 + lhi * 4) ^ sw)] = pk;
      }
    }

    // PV from cur
    __builtin_amdgcn_s_setprio(1);
    #pragma unroll
    for (int ks = 0; ks < 2; ++ks) {
      bf16x8 pa = *(const bf16x8*)&Pl[w][l15 * 64 + ((ks * 32 + lhi * 8) ^ SWZ(l15))];
      #pragma unroll
      for (int nf = 0; nf < 4; ++nf) {
        const int row = nf * 16 + l15;
        bf16x8 bv = *(const bf16x8*)&Vt[cur][row * 64 + ((ks * 32 + lhi * 8) ^ SWZ(row))];
        octx[nf] = __builtin_amdgcn_mfma_f32_16x16x32_bf16(pa, bv, octx[nf], 0, 0, 0);
      }
    }
    __builtin_amdgcn_s_setprio(0);

    barrier_lgkm();
  };

  for (int i2 = 0; i2 < 16; ++i2) {
    iter(2 * i2,     0, bfA);
    iter(2 * i2 + 1, 1, bfB);
  }

  // combine partial sums once, normalize, write
  s_run += __shfl_xor(s_run, 16);
  s_run += __shfl_xor(s_run, 32);
  const float inv = 1.0f / s_run;
  float invr[4];
  invr[0] = __shfl(inv, lhi * 4 + 0);
  invr[1] = __shfl(inv, lhi * 4 + 1);
  invr[2] = __shfl(inv, lhi * 4 + 2);
  invr[3] = __shfl(inv, lhi * 4 + 3);
  #pragma unroll
  for (int nf = 0; nf < 4; ++nf)
    #pragma unroll
    for (int r = 0; r < 4; ++r) {
      const int grow = b * 2048 + qt * 128 + w * 16 + lhi * 4 + r;
      const int gcol = h * 64 + nf * 16 + l15;
      ctx[(size_t)grow * 1024 + gcol] = f2bf(octx[nf][r] * invr[r]);
    }
}

// ---------- launch ----------
extern "C" void kernel_launch(void* const* d_in, const int* in_sizes, int n_in,
                              void* d_out, int out_size, void* d_ws, size_t ws_size,
                              hipStream_t stream) {
  const float* x    = (const float*)d_in[0];
  const float* rb   = (const float*)d_in[1];
  const float* wq   = (const float*)d_in[2];
  const float* wk   = (const float*)d_in[3];
  const float* wv   = (const float*)d_in[4];
  const float* wo   = (const float*)d_in[5];
  const float* wo_b = (const float*)d_in[6];
  const float* w1   = (const float*)d_in[7];
  const float* b1   = (const float*)d_in[8];
  const float* w2   = (const float*)d_in[9];
  const float* b2   = (const float*)d_in[10];
  const float* ln1g = (const float*)d_in[11];
  const float* ln1b = (const float*)d_in[12];
  const float* ln2g = (const float*)d_in[13];
  const float* ln2b = (const float*)d_in[14];

  char* ws = (char*)d_ws;
  u16*   xn    = (u16*)(ws + 0);                    //  8 MB
  u16*   qkvb  = (u16*)(ws + (8u << 20));           // 24 MB
  u16*   hbuf  = (u16*)(ws + (8u << 20));           // 32 MB (reuses qkv+ctx)
  u16*   ctxb  = (u16*)(ws + (32u << 20));          //  8 MB
  float* x1    = (float*)(ws + (40u << 20));        // 16 MB
  u16*   wqkvt = (u16*)(ws + (56u << 20));          //  6 MB
  u16*   wot   = (u16*)(ws + (62u << 20));          //  2 MB
  u16*   w1t   = (u16*)(ws + (64u << 20));          //  8 MB
  u16*   w2t   = (u16*)(ws + (72u << 20));          //  8 MB

  transpose_all<<<12288, 256, 0, stream>>>(wq, wk, wv, wo, w1, w2,
                                           wqkvt, wot, w1t, w2t);

  ln_kernel<<<4096, 256, 0, stream>>>(x, ln1g, ln1b, xn);
  gemm_bt<0><<<768, 256, 0, stream>>>(xn, wqkvt, qkvb, nullptr, nullptr, 4096, 3072, 1024, 32);
  attn_kernel<<<dim3(16, 32), 512, 0, stream>>>(qkvb, rb, ctxb);
  gemm_bt64<2><<<512, 256, 0, stream>>>(ctxb, wot, x1, wo_b, x, 4096, 1024, 1024, 64);
  ln_kernel<<<4096, 256, 0, stream>>>(x1, ln2g, ln2b, xn);
  gemm_bt<1><<<1024, 256, 0, stream>>>(xn, w1t, hbuf, b1, nullptr, 4096, 4096, 1024, 32);
  gemm_bt64<2><<<512, 256, 0, stream>>>(hbuf, w2t, (float*)d_out, b2, x1, 4096, 1024, 4096, 64);

  (void)in_sizes; (void)n_in; (void)out_size; (void)ws_size;
}